// Round 3
// baseline (507.605 us; speedup 1.0000x reference)
//
#include <hip/hip_runtime.h>
#include <hip/hip_bf16.h>
#include <math.h>

#define L1_     5248
#define LENRRC_ 129
#define TSTART_ 65
#define NWIN_   5120
#define SWZ(m) ((m) + ((m) >> 3))     // stride-8 reads -> stride-9 -> conflict-free

// ---------- z init with bias (for split-K atomic GEMM) ----------
__global__ __launch_bounds__(256) void initz_k(float* z, const float* bias) {
    int i = blockIdx.x * 256 + threadIdx.x;          // 524288 total
    z[i] = bias[i & 511];
}

// ---------- tiled GEMM: C[M,N] = A[M,K] @ W[K,N] (+bias), all fp32 ----------
template<int BM, int BN, int BK, int TM, int TN, int SK>
__global__ __launch_bounds__(256) void gemm_k(const float* __restrict__ A,
        const float* __restrict__ W, const float* __restrict__ bias,
        float* __restrict__ C, int M, int N, int K)
{
    __shared__ float As[BK][BM];
    __shared__ float Bs[BK][BN];
    constexpr int NX = BN / TN;
    const int tid = threadIdx.x;
    const int tx = tid % NX, ty = tid / NX;
    const int m0 = blockIdx.y * BM, n0 = blockIdx.x * BN;
    int kbeg = 0, kend = K;
    if (SK > 1) { int kch = K / SK; kbeg = blockIdx.z * kch; kend = kbeg + kch; }
    float acc[TM][TN] = {};
    for (int kt = kbeg; kt < kend; kt += BK) {
        for (int e = tid; e < BM * BK; e += 256) {
            int m = e / BK, kk = e % BK;
            As[kk][m] = A[(size_t)(m0 + m) * K + kt + kk];
        }
        for (int e = tid; e < BK * BN; e += 256) {
            int kk = e / BN, n = e % BN;
            Bs[kk][n] = W[(size_t)(kt + kk) * N + n0 + n];
        }
        __syncthreads();
        #pragma unroll
        for (int kk = 0; kk < BK; ++kk) {
            float av[TM], bv[TN];
            #pragma unroll
            for (int i = 0; i < TM; ++i) av[i] = As[kk][ty * TM + i];
            #pragma unroll
            for (int j = 0; j < TN; ++j) bv[j] = Bs[kk][tx * TN + j];
            #pragma unroll
            for (int i = 0; i < TM; ++i)
                #pragma unroll
                for (int j = 0; j < TN; ++j) acc[i][j] += av[i] * bv[j];
        }
        __syncthreads();
    }
    #pragma unroll
    for (int i = 0; i < TM; ++i) {
        int m = m0 + ty * TM + i;
        #pragma unroll
        for (int j = 0; j < TN; ++j) {
            int n = n0 + tx * TN + j;
            if constexpr (SK > 1) {
                atomicAdd(&C[(size_t)m * N + n], acc[i][j]);
            } else {
                C[(size_t)m * N + n] = acc[i][j] + bias[n];
            }
        }
    }
}

// ---------- megakernel: one block per batch row, whole signal chain in LDS ----------
__global__ __launch_bounds__(256) void mega_k(const float* __restrict__ z,
        const float* __restrict__ rrc, const float* __restrict__ awgn,
        const int* __restrict__ slocp, float* __restrict__ y5, float* __restrict__ papr,
        float* __restrict__ out_papr)
{
    __shared__ float zl[512];
    __shared__ float fr[8][32], fi[8][32];
    __shared__ float trl[640], til[640];
    __shared__ float hl[LENRRC_];
    __shared__ float csl[16], ssl[16];
    __shared__ float c64[64], s64[64];
    __shared__ float dxr[SWZ(L1_ - 1) + 1];
    __shared__ float wrl[512], wil[512];
    __shared__ float red[256], red2[256];

    const int b = blockIdx.x, tid = threadIdx.x;
    const int sloc = *slocp;

    // ---- tables + z row load ----
    if (tid < 64) {
        float ang = 0.09817477042468103f * (float)tid;   // 2pi/64
        float s, c; sincosf(ang, &s, &c);
        c64[tid] = c; s64[tid] = s;
    }
    if (tid >= 64 && tid < 80) {
        int t = tid - 64;
        float ang = 1.9634954084936207f * (float)t;      // 2pi*5/16
        float s, c; sincosf(ang, &s, &c);
        csl[t] = 1.4142135623730951f * c; ssl[t] = 1.4142135623730951f * s;
    }
    for (int e = tid; e < LENRRC_; e += 256) hl[e] = rrc[e];
    float v0 = z[(size_t)b * 512 + tid];
    float v1 = z[(size_t)b * 512 + tid + 256];

    // ---- power norm (mean/std ddof=1) ----
    red[tid] = v0 + v1; __syncthreads();
    for (int s = 128; s > 0; s >>= 1) { if (tid < s) red[tid] += red[tid + s]; __syncthreads(); }
    float mean = red[0] * (1.f / 512.f);
    __syncthreads();
    float d0 = v0 - mean, d1 = v1 - mean;
    red[tid] = d0 * d0 + d1 * d1; __syncthreads();
    for (int s = 128; s > 0; s >>= 1) { if (tid < s) red[tid] += red[tid + s]; __syncthreads(); }
    float inv = 1.f / (sqrtf(red[0] / 511.f) + 1e-8f);
    zl[tid] = d0 * inv; zl[tid + 256] = d1 * inv;
    __syncthreads();

    // ---- P1: DFT32 (+fftshift folded): fr[s][k] = DFT at freq (k+16)&31 ----
    {
        int s = tid >> 5, kk = tid & 31;
        int kk2 = (kk + 16) & 31;
        float sr = 0.f, si = 0.f;
        for (int q = 0; q < 32; ++q) {
            int t = 2 * ((q * kk2) & 31);                // 2pi*t/32 via 64-table
            float cth = c64[t], sth = s64[t];
            float cr = zl[(s * 32 + q) * 2], ci = zl[(s * 32 + q) * 2 + 1];
            sr += cr * cth + ci * sth;                   // * e^{-i ang}
            si += ci * cth - cr * sth;
        }
        fr[s][kk] = sr * 0.1767766952966369f;            // 1/sqrt(32)
        fi[s][kk] = si * 0.1767766952966369f;
    }
    __syncthreads();

    // ---- P2: IDFT64 + CP -> trl/til (len 640) ----
    for (int e = tid; e < 512; e += 256) {
        int s = e >> 6, n = e & 63;
        float dr = 0.f, di = 0.f;
        for (int k = 0; k < 32; ++k) {
            int t = ((sloc + k) * n) & 63;
            float cth = c64[t], sth = s64[t];
            dr += fr[s][k] * cth - fi[s][k] * sth;       // * e^{+i ang}
            di += fi[s][k] * cth + fr[s][k] * sth;
        }
        dr *= 0.125f; di *= 0.125f;                      // 1/sqrt(64)
        int base = s * 80;
        trl[base + 16 + n] = dr; til[base + 16 + n] = di;
        if (n >= 48) { trl[base + n - 48] = dr; til[base + n - 48] = di; }  // CP
    }
    __syncthreads();

    // ---- P3: upsample x8 + RRC (polyphase) + carrier -> dxr (swizzled), sumsq ----
    float ss = 0.f;
    for (int a = tid; a < 656; a += 256) {
        float accr[8] = {}, acci[8] = {};
        for (int d = 0; d <= 16; ++d) {
            int m = a - d;
            bool ok = (m >= 0) && (m < 640);
            float vr = ok ? trl[m] : 0.f;
            float vi = ok ? til[m] : 0.f;
            #pragma unroll
            for (int r = 0; r < 8; ++r) {
                int tap = r + 8 * d;
                if (tap <= 128) { float h = hl[tap]; accr[r] += vr * h; acci[r] += vi * h; }
            }
        }
        #pragma unroll
        for (int r = 0; r < 8; ++r) {
            int i = a * 8 + r;
            float v = accr[r] * csl[i & 15] - acci[r] * ssl[i & 15];
            dxr[SWZ(i)] = v;
            ss += v * v;
        }
    }
    red[tid] = ss; __syncthreads();
    for (int s = 128; s > 0; s >>= 1) { if (tid < s) red[tid] += red[tid + s]; __syncthreads(); }
    float thr = 1.2f * sqrtf(red[0] / (float)L1_);
    __syncthreads();

    // ---- P5: clip + PAPR window stats + AWGN (in place) ----
    float pmax = 0.f, psum = 0.f;
    for (int i = tid; i < L1_; i += 256) {
        float x = dxr[SWZ(i)];
        float ax = fabsf(x);
        float over = ax - thr; over = over > 0.f ? over : 0.f;
        float y = (1.f - over / (ax + 1e-8f)) * x;
        if (i >= TSTART_ && i < TSTART_ + NWIN_) { float p = y * y; psum += p; pmax = fmaxf(pmax, p); }
        dxr[SWZ(i)] = y + awgn[(size_t)b * L1_ + i];
    }
    red[tid] = psum; red2[tid] = pmax; __syncthreads();
    for (int s = 128; s > 0; s >>= 1) {
        if (tid < s) { red[tid] += red[tid + s]; red2[tid] = fmaxf(red2[tid], red2[tid + s]); }
        __syncthreads();
    }
    if (tid == 0) {
        float pdb = 10.f * log10f(red2[0] / (red[0] / (float)NWIN_));
        papr[b] = pdb;
        out_papr[b] = pdb;
    }
    __syncthreads();

    // ---- P6: matched RRC filter at needed taps, carrier folded in ----
    for (int j = tid; j < 512; j += 256) {
        int s = j >> 6, n = j & 63;
        int Nf = 128 + 8 * (s * 80 + 16 + n);
        float ar = 0.f, ai = 0.f;
        for (int d = 0; d <= 128; ++d) {
            int m = Nf - d;                              // always in [0, L1)
            float v = dxr[SWZ(m)];
            float h = hl[d];
            ar += v * csl[m & 15] * h;
            ai += v * ssl[m & 15] * h;
        }
        wrl[j] = ar;
        wil[j] = -ai;                                    // rc.im = -data_r*sin
    }
    __syncthreads();

    // ---- P7: DFT64 -> select band [sloc, sloc+32) -> fftshift (folded) ----
    {
        int s = tid >> 5, kk = tid & 31;
        int f = sloc + kk;
        float vr = 0.f, vi = 0.f;
        for (int n = 0; n < 64; ++n) {
            int t = (f * n) & 63;
            float cth = c64[t], sth = s64[t];
            float wr = wrl[s * 64 + n], wi = wil[s * 64 + n];
            vr += wr * cth + wi * sth;                   // * e^{-i ang}
            vi += wi * cth - wr * sth;
        }
        int ksh = (kk + 16) & 31;                        // fftshift
        fr[s][ksh] = vr * 0.125f;
        fi[s][ksh] = vi * 0.125f;
    }
    __syncthreads();

    // ---- P8: IDFT32 -> y5 (interleaved re/im) ----
    {
        int s = tid >> 5, q = tid & 31;
        float ur = 0.f, ui = 0.f;
        for (int k = 0; k < 32; ++k) {
            int t = 2 * ((k * q) & 31);
            float cth = c64[t], sth = s64[t];
            ur += fr[s][k] * cth - fi[s][k] * sth;       // * e^{+i ang}
            ui += fi[s][k] * cth + fr[s][k] * sth;
        }
        ur *= 0.1767766952966369f; ui *= 0.1767766952966369f;
        y5[(size_t)b * 512 + (s * 32 + q) * 2]     = ur;
        y5[(size_t)b * 512 + (s * 32 + q) * 2 + 1] = ui;
    }
}

__global__ __launch_bounds__(256) void loss_k(const float* __restrict__ papr,
        float* out_loss) {
    __shared__ float red[256];
    int tid = threadIdx.x; float s = 0.f;
    for (int i = tid; i < 1024; i += 256) { float v = papr[i] - 8.f; s += v > 0.f ? v : 0.f; }
    red[tid] = s; __syncthreads();
    for (int k = 128; k > 0; k >>= 1) { if (tid < k) red[tid] += red[tid + k]; __syncthreads(); }
    if (tid == 0) *out_loss = red[0] * (1.f / 1024.f);
}

extern "C" void kernel_launch(void* const* d_in, const int* in_sizes, int n_in,
                              void* d_out, int out_size, void* d_ws, size_t ws_size,
                              hipStream_t stream) {
    const float* x    = (const float*)d_in[0];
    const float* Wenc = (const float*)d_in[1];
    const float* benc = (const float*)d_in[2];
    const float* Wdec = (const float*)d_in[3];
    const float* bdec = (const float*)d_in[4];
    const float* rrc  = (const float*)d_in[5];
    const float* awgn = (const float*)d_in[6];
    const int* sloc   = (const int*)d_in[7];
    float* out = (float*)d_out;

    float* ws   = (float*)d_ws;
    float* z    = ws;                    // 1024*512
    float* y5   = z  + 524288;           // 1024*512
    float* papr = y5 + 524288;           // 1024
    // total ws: 1,049,600 floats = 4.2 MB

    float* out_papr = out + (size_t)1024 * 3072;
    float* out_loss = out_papr + 1024;

    initz_k<<<2048, 256, 0, stream>>>(z, benc);
    gemm_k<64, 64, 16, 4, 4, 2>
        <<<dim3(8, 16, 2), 256, 0, stream>>>(x, Wenc, benc, z, 1024, 512, 3072);
    mega_k<<<1024, 256, 0, stream>>>(z, rrc, awgn, sloc, y5, papr, out_papr);
    loss_k<<<1, 256, 0, stream>>>(papr, out_loss);
    gemm_k<64, 64, 16, 4, 4, 1>
        <<<dim3(48, 16, 1), 256, 0, stream>>>(y5, Wdec, bdec, out, 1024, 3072, 512);
}

// Round 4
// 280.198 us; speedup vs baseline: 1.8116x; 1.8116x over previous
//
#include <hip/hip_runtime.h>
#include <hip/hip_bf16.h>
#include <math.h>

#define L1_     5248
#define LENRRC_ 129
#define TSTART_ 65
#define NWIN_   5120
#define SWZ(m) ((m) + ((m) >> 3))     // stride-8 reads -> stride-9 -> conflict-free

typedef __attribute__((ext_vector_type(8))) short s16x8;   // 8 bf16 lanes (4 VGPRs)
typedef __attribute__((ext_vector_type(4))) float f32x4;   // MFMA accumulator

// pack fp32 -> (hi bf16 in high16 | lo bf16 in low16); hi is RNE, lo truncated
__device__ inline unsigned pack_pair(float x) {
    unsigned xb = __float_as_uint(x);
    unsigned hi = (xb + 0x7fffu + ((xb >> 16) & 1u)) & 0xffff0000u;
    float lof = x - __uint_as_float(hi);
    return hi | (__float_as_uint(lof) >> 16);
}

// ---------- z init with bias (for split-K atomic GEMM) ----------
__global__ __launch_bounds__(256) void initz_k(float* z, const float* bias) {
    int i = blockIdx.x * 256 + threadIdx.x;          // 524288 total
    z[i] = bias[i & 511];
}

// ---------- MFMA GEMM, split bf16 (hi/lo): C[M,N] (+)= A[M,K]@W[K,N] (+bias) ----
// BM=BN=128, BK=32, 256 threads = 4 waves (2x2), wave tile 64x64.
template<int SK, bool ATOMIC>
__global__ __launch_bounds__(256) void gemm_mfma_k(const float* __restrict__ A,
        const float* __restrict__ W, const float* __restrict__ bias,
        float* __restrict__ C, int M, int N, int K)
{
    __shared__ unsigned Asl[128 * 36];   // [m][k] packed, row stride 36 (16B-aligned frags)
    __shared__ unsigned Bsl[128 * 36];   // [n][k] packed (B transposed)
    const int tid = threadIdx.x;
    const int lane = tid & 63, wave = tid >> 6;
    const int wm = (wave >> 1) * 64, wn = (wave & 1) * 64;
    const int m0 = blockIdx.y * 128, n0 = blockIdx.x * 128;
    int kbeg = 0, kend = K;
    if (SK > 1) { int kch = K / SK; kbeg = blockIdx.z * kch; kend = kbeg + kch; }
    f32x4 acc[4][4] = {};
    const int fm = lane & 15, q = lane >> 4;

    for (int kt = kbeg; kt < kend; kt += 32) {
        #pragma unroll
        for (int i = 0; i < 4; ++i) {            // stage A tile 128x32
            int flat = i * 1024 + tid * 4;
            int m = flat >> 5, k = flat & 31;
            const float4 v = *(const float4*)(A + (size_t)(m0 + m) * K + kt + k);
            Asl[m * 36 + k]     = pack_pair(v.x);
            Asl[m * 36 + k + 1] = pack_pair(v.y);
            Asl[m * 36 + k + 2] = pack_pair(v.z);
            Asl[m * 36 + k + 3] = pack_pair(v.w);
        }
        #pragma unroll
        for (int i = 0; i < 4; ++i) {            // stage B tile 32x128 (transpose)
            int flat = i * 1024 + tid * 4;
            int k = flat >> 7, n = flat & 127;
            const float4 v = *(const float4*)(W + (size_t)(kt + k) * N + n0 + n);
            Bsl[n * 36 + k]       = pack_pair(v.x);
            Bsl[(n + 1) * 36 + k] = pack_pair(v.y);
            Bsl[(n + 2) * 36 + k] = pack_pair(v.z);
            Bsl[(n + 3) * 36 + k] = pack_pair(v.w);
        }
        __syncthreads();

        s16x8 ah[4], al[4], bh[4], bl[4];
        #pragma unroll
        for (int mf = 0; mf < 4; ++mf) {         // A frags: 8 contiguous k per lane
            const uint4* p = (const uint4*)&Asl[(wm + mf * 16 + fm) * 36 + q * 8];
            uint4 p0 = p[0], p1 = p[1];
            uint4 hu, lu;
            hu.x = (p0.x >> 16) | (p0.y & 0xffff0000u);
            hu.y = (p0.z >> 16) | (p0.w & 0xffff0000u);
            hu.z = (p1.x >> 16) | (p1.y & 0xffff0000u);
            hu.w = (p1.z >> 16) | (p1.w & 0xffff0000u);
            lu.x = (p0.x & 0xffffu) | (p0.y << 16);
            lu.y = (p0.z & 0xffffu) | (p0.w << 16);
            lu.z = (p1.x & 0xffffu) | (p1.y << 16);
            lu.w = (p1.z & 0xffffu) | (p1.w << 16);
            ah[mf] = __builtin_bit_cast(s16x8, hu);
            al[mf] = __builtin_bit_cast(s16x8, lu);
        }
        #pragma unroll
        for (int nf = 0; nf < 4; ++nf) {         // B frags
            const uint4* p = (const uint4*)&Bsl[(wn + nf * 16 + fm) * 36 + q * 8];
            uint4 p0 = p[0], p1 = p[1];
            uint4 hu, lu;
            hu.x = (p0.x >> 16) | (p0.y & 0xffff0000u);
            hu.y = (p0.z >> 16) | (p0.w & 0xffff0000u);
            hu.z = (p1.x >> 16) | (p1.y & 0xffff0000u);
            hu.w = (p1.z >> 16) | (p1.w & 0xffff0000u);
            lu.x = (p0.x & 0xffffu) | (p0.y << 16);
            lu.y = (p0.z & 0xffffu) | (p0.w << 16);
            lu.z = (p1.x & 0xffffu) | (p1.y << 16);
            lu.w = (p1.z & 0xffffu) | (p1.w << 16);
            bh[nf] = __builtin_bit_cast(s16x8, hu);
            bl[nf] = __builtin_bit_cast(s16x8, lu);
        }
        #pragma unroll
        for (int mf = 0; mf < 4; ++mf)
            #pragma unroll
            for (int nf = 0; nf < 4; ++nf) {
                acc[mf][nf] = __builtin_amdgcn_mfma_f32_16x16x32_bf16(ah[mf], bh[nf], acc[mf][nf], 0, 0, 0);
                acc[mf][nf] = __builtin_amdgcn_mfma_f32_16x16x32_bf16(ah[mf], bl[nf], acc[mf][nf], 0, 0, 0);
                acc[mf][nf] = __builtin_amdgcn_mfma_f32_16x16x32_bf16(al[mf], bh[nf], acc[mf][nf], 0, 0, 0);
            }
        __syncthreads();
    }

    #pragma unroll
    for (int mf = 0; mf < 4; ++mf)
        #pragma unroll
        for (int nf = 0; nf < 4; ++nf)
            #pragma unroll
            for (int r = 0; r < 4; ++r) {
                int m = m0 + wm + mf * 16 + (lane >> 4) * 4 + r;
                int n = n0 + wn + nf * 16 + (lane & 15);
                if constexpr (ATOMIC) atomicAdd(&C[(size_t)m * N + n], acc[mf][nf][r]);
                else C[(size_t)m * N + n] = acc[mf][nf][r] + bias[n];
            }
}

// ---------- megakernel: one block per batch row, whole signal chain in LDS ----------
__global__ __launch_bounds__(256) void mega_k(const float* __restrict__ z,
        const float* __restrict__ rrc, const float* __restrict__ awgn,
        const int* __restrict__ slocp, float* __restrict__ y5, float* __restrict__ papr,
        float* __restrict__ out_papr)
{
    __shared__ float zl[512];
    __shared__ float fr[8][32], fi[8][32];
    __shared__ float trl[640], til[640];
    __shared__ float hl[LENRRC_];
    __shared__ float csl[16], ssl[16];
    __shared__ float c64[64], s64[64];
    __shared__ float dxr[SWZ(L1_ - 1) + 1];
    __shared__ float wrl[512], wil[512];
    __shared__ float red[256], red2[256];

    const int b = blockIdx.x, tid = threadIdx.x;
    const int sloc = *slocp;

    if (tid < 64) {
        float ang = 0.09817477042468103f * (float)tid;   // 2pi/64
        float s, c; sincosf(ang, &s, &c);
        c64[tid] = c; s64[tid] = s;
    }
    if (tid >= 64 && tid < 80) {
        int t = tid - 64;
        float ang = 1.9634954084936207f * (float)t;      // 2pi*5/16
        float s, c; sincosf(ang, &s, &c);
        csl[t] = 1.4142135623730951f * c; ssl[t] = 1.4142135623730951f * s;
    }
    for (int e = tid; e < LENRRC_; e += 256) hl[e] = rrc[e];
    float v0 = z[(size_t)b * 512 + tid];
    float v1 = z[(size_t)b * 512 + tid + 256];

    // ---- power norm (mean/std ddof=1) ----
    red[tid] = v0 + v1; __syncthreads();
    for (int s = 128; s > 0; s >>= 1) { if (tid < s) red[tid] += red[tid + s]; __syncthreads(); }
    float mean = red[0] * (1.f / 512.f);
    __syncthreads();
    float d0 = v0 - mean, d1 = v1 - mean;
    red[tid] = d0 * d0 + d1 * d1; __syncthreads();
    for (int s = 128; s > 0; s >>= 1) { if (tid < s) red[tid] += red[tid + s]; __syncthreads(); }
    float inv = 1.f / (sqrtf(red[0] / 511.f) + 1e-8f);
    zl[tid] = d0 * inv; zl[tid + 256] = d1 * inv;
    __syncthreads();

    // ---- P1: DFT32 (+fftshift folded) ----
    {
        int s = tid >> 5, kk = tid & 31;
        int kk2 = (kk + 16) & 31;
        float sr = 0.f, si = 0.f;
        for (int q = 0; q < 32; ++q) {
            int t = 2 * ((q * kk2) & 31);
            float cth = c64[t], sth = s64[t];
            float cr = zl[(s * 32 + q) * 2], ci = zl[(s * 32 + q) * 2 + 1];
            sr += cr * cth + ci * sth;
            si += ci * cth - cr * sth;
        }
        fr[s][kk] = sr * 0.1767766952966369f;
        fi[s][kk] = si * 0.1767766952966369f;
    }
    __syncthreads();

    // ---- P2: IDFT64 + CP ----
    for (int e = tid; e < 512; e += 256) {
        int s = e >> 6, n = e & 63;
        float dr = 0.f, di = 0.f;
        for (int k = 0; k < 32; ++k) {
            int t = ((sloc + k) * n) & 63;
            float cth = c64[t], sth = s64[t];
            dr += fr[s][k] * cth - fi[s][k] * sth;
            di += fi[s][k] * cth + fr[s][k] * sth;
        }
        dr *= 0.125f; di *= 0.125f;
        int base = s * 80;
        trl[base + 16 + n] = dr; til[base + 16 + n] = di;
        if (n >= 48) { trl[base + n - 48] = dr; til[base + n - 48] = di; }
    }
    __syncthreads();

    // ---- P3: upsample x8 + RRC polyphase + carrier -> dxr (swizzled), sumsq ----
    float ss = 0.f;
    for (int a = tid; a < 656; a += 256) {
        float accr[8] = {}, acci[8] = {};
        for (int d = 0; d <= 16; ++d) {
            int m = a - d;
            bool ok = (m >= 0) && (m < 640);
            float vr = ok ? trl[m] : 0.f;
            float vi = ok ? til[m] : 0.f;
            #pragma unroll
            for (int r = 0; r < 8; ++r) {
                int tap = r + 8 * d;
                if (tap <= 128) { float h = hl[tap]; accr[r] += vr * h; acci[r] += vi * h; }
            }
        }
        #pragma unroll
        for (int r = 0; r < 8; ++r) {
            int i = a * 8 + r;
            float v = accr[r] * csl[i & 15] - acci[r] * ssl[i & 15];
            dxr[SWZ(i)] = v;
            ss += v * v;
        }
    }
    red[tid] = ss; __syncthreads();
    for (int s = 128; s > 0; s >>= 1) { if (tid < s) red[tid] += red[tid + s]; __syncthreads(); }
    float thr = 1.2f * sqrtf(red[0] / (float)L1_);
    __syncthreads();

    // ---- P5: clip + PAPR window stats + AWGN ----
    float pmax = 0.f, psum = 0.f;
    for (int i = tid; i < L1_; i += 256) {
        float x = dxr[SWZ(i)];
        float ax = fabsf(x);
        float over = ax - thr; over = over > 0.f ? over : 0.f;
        float y = (1.f - over / (ax + 1e-8f)) * x;
        if (i >= TSTART_ && i < TSTART_ + NWIN_) { float p = y * y; psum += p; pmax = fmaxf(pmax, p); }
        dxr[SWZ(i)] = y + awgn[(size_t)b * L1_ + i];
    }
    red[tid] = psum; red2[tid] = pmax; __syncthreads();
    for (int s = 128; s > 0; s >>= 1) {
        if (tid < s) { red[tid] += red[tid + s]; red2[tid] = fmaxf(red2[tid], red2[tid + s]); }
        __syncthreads();
    }
    if (tid == 0) {
        float pdb = 10.f * log10f(red2[0] / (red[0] / (float)NWIN_));
        papr[b] = pdb;
        out_papr[b] = pdb;
    }
    __syncthreads();

    // ---- P6: matched RRC filter, carrier folded in ----
    for (int j = tid; j < 512; j += 256) {
        int s = j >> 6, n = j & 63;
        int Nf = 128 + 8 * (s * 80 + 16 + n);
        float ar = 0.f, ai = 0.f;
        for (int d = 0; d <= 128; ++d) {
            int m = Nf - d;
            float v = dxr[SWZ(m)];
            float h = hl[d];
            ar += v * csl[m & 15] * h;
            ai += v * ssl[m & 15] * h;
        }
        wrl[j] = ar;
        wil[j] = -ai;
    }
    __syncthreads();

    // ---- P7: DFT64 -> band select -> fftshift ----
    {
        int s = tid >> 5, kk = tid & 31;
        int f = sloc + kk;
        float vr = 0.f, vi = 0.f;
        for (int n = 0; n < 64; ++n) {
            int t = (f * n) & 63;
            float cth = c64[t], sth = s64[t];
            float wr = wrl[s * 64 + n], wi = wil[s * 64 + n];
            vr += wr * cth + wi * sth;
            vi += wi * cth - wr * sth;
        }
        int ksh = (kk + 16) & 31;
        fr[s][ksh] = vr * 0.125f;
        fi[s][ksh] = vi * 0.125f;
    }
    __syncthreads();

    // ---- P8: IDFT32 -> y5 ----
    {
        int s = tid >> 5, q2 = tid & 31;
        float ur = 0.f, ui = 0.f;
        for (int k = 0; k < 32; ++k) {
            int t = 2 * ((k * q2) & 31);
            float cth = c64[t], sth = s64[t];
            ur += fr[s][k] * cth - fi[s][k] * sth;
            ui += fi[s][k] * cth + fr[s][k] * sth;
        }
        ur *= 0.1767766952966369f; ui *= 0.1767766952966369f;
        y5[(size_t)b * 512 + (s * 32 + q2) * 2]     = ur;
        y5[(size_t)b * 512 + (s * 32 + q2) * 2 + 1] = ui;
    }
}

__global__ __launch_bounds__(256) void loss_k(const float* __restrict__ papr,
        float* out_loss) {
    __shared__ float red[256];
    int tid = threadIdx.x; float s = 0.f;
    for (int i = tid; i < 1024; i += 256) { float v = papr[i] - 8.f; s += v > 0.f ? v : 0.f; }
    red[tid] = s; __syncthreads();
    for (int k = 128; k > 0; k >>= 1) { if (tid < k) red[tid] += red[tid + k]; __syncthreads(); }
    if (tid == 0) *out_loss = red[0] * (1.f / 1024.f);
}

extern "C" void kernel_launch(void* const* d_in, const int* in_sizes, int n_in,
                              void* d_out, int out_size, void* d_ws, size_t ws_size,
                              hipStream_t stream) {
    const float* x    = (const float*)d_in[0];
    const float* Wenc = (const float*)d_in[1];
    const float* benc = (const float*)d_in[2];
    const float* Wdec = (const float*)d_in[3];
    const float* bdec = (const float*)d_in[4];
    const float* rrc  = (const float*)d_in[5];
    const float* awgn = (const float*)d_in[6];
    const int* sloc   = (const int*)d_in[7];
    float* out = (float*)d_out;

    float* ws   = (float*)d_ws;
    float* z    = ws;                    // 1024*512
    float* y5   = z  + 524288;           // 1024*512
    float* papr = y5 + 524288;           // 1024

    float* out_papr = out + (size_t)1024 * 3072;
    float* out_loss = out_papr + 1024;

    initz_k<<<2048, 256, 0, stream>>>(z, benc);
    gemm_mfma_k<8, true>
        <<<dim3(4, 8, 8), 256, 0, stream>>>(x, Wenc, nullptr, z, 1024, 512, 3072);
    mega_k<<<1024, 256, 0, stream>>>(z, rrc, awgn, sloc, y5, papr, out_papr);
    loss_k<<<1, 256, 0, stream>>>(papr, out_loss);
    gemm_mfma_k<1, false>
        <<<dim3(24, 8, 1), 256, 0, stream>>>(y5, Wdec, bdec, out, 1024, 3072, 512);
}

// Round 6
// 217.686 us; speedup vs baseline: 2.3318x; 1.2872x over previous
//
#include <hip/hip_runtime.h>
#include <hip/hip_bf16.h>
#include <math.h>

#define L1_     5248
#define LENRRC_ 129
#define TSTART_ 65
#define NWIN_   5120
#define SWZ(m) ((m) + ((m) >> 3))     // stride-8 reads -> stride-9 -> conflict-free

typedef __attribute__((ext_vector_type(8))) short s16x8;   // 8 bf16 lanes (4 VGPRs)
typedef __attribute__((ext_vector_type(4))) float f32x4;   // MFMA accumulator

// pack fp32 -> (hi bf16 in high16 | lo bf16 in low16); hi is RNE, lo truncated
__device__ inline unsigned pack_pair(float x) {
    unsigned xb = __float_as_uint(x);
    unsigned hi = (xb + 0x7fffu + ((xb >> 16) & 1u)) & 0xffff0000u;
    float lof = x - __uint_as_float(hi);
    return hi | (__float_as_uint(lof) >> 16);
}

__device__ inline float wave_sum(float v) {
    #pragma unroll
    for (int m = 32; m > 0; m >>= 1) v += __shfl_xor(v, m, 64);
    return v;
}
__device__ inline float wave_max(float v) {
    #pragma unroll
    for (int m = 32; m > 0; m >>= 1) v = fmaxf(v, __shfl_xor(v, m, 64));
    return v;
}

// ---------- z init with bias (for split-K atomic GEMM) ----------
__global__ __launch_bounds__(256) void initz_k(float* z, const float* bias) {
    int i = blockIdx.x * 256 + threadIdx.x;          // 524288 total
    z[i] = bias[i & 511];
}

// ---------- MFMA GEMM, split bf16 hi/lo, BM=BN=64 BK=32, 4 waves 2x2 ----------
template<int SK, bool ATOMIC>
__global__ __launch_bounds__(256) void gemm_mfma_k(const float* __restrict__ A,
        const float* __restrict__ W, const float* __restrict__ bias,
        float* __restrict__ C, int M, int N, int K)
{
    __shared__ unsigned Asl[64 * 36];   // [m][k] packed hi|lo, row stride 36
    __shared__ unsigned Bsl[64 * 36];   // [n][k] packed (B transposed)
    const int tid = threadIdx.x;
    const int lane = tid & 63, wave = tid >> 6;
    const int wm = (wave >> 1) * 32, wn = (wave & 1) * 32;
    const int m0 = blockIdx.y * 64, n0 = blockIdx.x * 64;
    int kbeg = 0, kend = K;
    if (SK > 1) { int kch = K / SK; kbeg = blockIdx.z * kch; kend = kbeg + kch; }
    f32x4 acc[2][2] = {};
    const int fm = lane & 15, q = lane >> 4;

    for (int kt = kbeg; kt < kend; kt += 32) {
        #pragma unroll
        for (int i = 0; i < 2; ++i) {            // A tile 64x32
            int flat = i * 1024 + tid * 4;
            int m = flat >> 5, k = flat & 31;
            const float4 v = *(const float4*)(A + (size_t)(m0 + m) * K + kt + k);
            uint4 pk;
            pk.x = pack_pair(v.x); pk.y = pack_pair(v.y);
            pk.z = pack_pair(v.z); pk.w = pack_pair(v.w);
            *(uint4*)&Asl[m * 36 + k] = pk;      // ds_write_b128
        }
        #pragma unroll
        for (int i = 0; i < 2; ++i) {            // B tile 32x64 (transpose)
            int flat = i * 1024 + tid * 4;
            int kk = flat >> 6, n = flat & 63;
            const float4 v = *(const float4*)(W + (size_t)(kt + kk) * N + n0 + n);
            Bsl[n * 36 + kk]       = pack_pair(v.x);
            Bsl[(n + 1) * 36 + kk] = pack_pair(v.y);
            Bsl[(n + 2) * 36 + kk] = pack_pair(v.z);
            Bsl[(n + 3) * 36 + kk] = pack_pair(v.w);
        }
        __syncthreads();

        s16x8 ah[2], al[2], bh[2], bl[2];
        #pragma unroll
        for (int mf = 0; mf < 2; ++mf) {
            const uint4* p = (const uint4*)&Asl[(wm + mf * 16 + fm) * 36 + q * 8];
            uint4 p0 = p[0], p1 = p[1];
            uint4 hu, lu;
            hu.x = (p0.x >> 16) | (p0.y & 0xffff0000u);
            hu.y = (p0.z >> 16) | (p0.w & 0xffff0000u);
            hu.z = (p1.x >> 16) | (p1.y & 0xffff0000u);
            hu.w = (p1.z >> 16) | (p1.w & 0xffff0000u);
            lu.x = (p0.x & 0xffffu) | (p0.y << 16);
            lu.y = (p0.z & 0xffffu) | (p0.w << 16);
            lu.z = (p1.x & 0xffffu) | (p1.y << 16);
            lu.w = (p1.z & 0xffffu) | (p1.w << 16);
            ah[mf] = __builtin_bit_cast(s16x8, hu);
            al[mf] = __builtin_bit_cast(s16x8, lu);
        }
        #pragma unroll
        for (int nf = 0; nf < 2; ++nf) {
            const uint4* p = (const uint4*)&Bsl[(wn + nf * 16 + fm) * 36 + q * 8];
            uint4 p0 = p[0], p1 = p[1];
            uint4 hu, lu;
            hu.x = (p0.x >> 16) | (p0.y & 0xffff0000u);
            hu.y = (p0.z >> 16) | (p0.w & 0xffff0000u);
            hu.z = (p1.x >> 16) | (p1.y & 0xffff0000u);
            hu.w = (p1.z >> 16) | (p1.w & 0xffff0000u);
            lu.x = (p0.x & 0xffffu) | (p0.y << 16);
            lu.y = (p0.z & 0xffffu) | (p0.w << 16);
            lu.z = (p1.x & 0xffffu) | (p1.y << 16);
            lu.w = (p1.z & 0xffffu) | (p1.w << 16);
            bh[nf] = __builtin_bit_cast(s16x8, hu);
            bl[nf] = __builtin_bit_cast(s16x8, lu);
        }
        #pragma unroll
        for (int mf = 0; mf < 2; ++mf)
            #pragma unroll
            for (int nf = 0; nf < 2; ++nf) {
                acc[mf][nf] = __builtin_amdgcn_mfma_f32_16x16x32_bf16(ah[mf], bh[nf], acc[mf][nf], 0, 0, 0);
                acc[mf][nf] = __builtin_amdgcn_mfma_f32_16x16x32_bf16(ah[mf], bl[nf], acc[mf][nf], 0, 0, 0);
                acc[mf][nf] = __builtin_amdgcn_mfma_f32_16x16x32_bf16(al[mf], bh[nf], acc[mf][nf], 0, 0, 0);
            }
        __syncthreads();
    }

    #pragma unroll
    for (int mf = 0; mf < 2; ++mf)
        #pragma unroll
        for (int nf = 0; nf < 2; ++nf)
            #pragma unroll
            for (int r = 0; r < 4; ++r) {
                int m = m0 + wm + mf * 16 + q * 4 + r;
                int n = n0 + wn + nf * 16 + fm;
                if constexpr (ATOMIC) atomicAdd(&C[(size_t)m * N + n], acc[mf][nf][r]);
                else C[(size_t)m * N + n] = acc[mf][nf][r] + bias[n];
            }
}

// ---------- megakernel: one block per batch row, whole signal chain in LDS ----------
__global__ __launch_bounds__(256) void mega_k(const float* __restrict__ z,
        const float* __restrict__ rrc, const float* __restrict__ awgn,
        const int* __restrict__ slocp, float* __restrict__ y5, float* __restrict__ papr,
        float* __restrict__ out_papr)
{
    __shared__ float  zl[512];
    __shared__ float2 frfi[8][32];
    __shared__ float2 trti[640];
    __shared__ float  hl[132];
    __shared__ float  csl[16], ssl[16];
    __shared__ float2 cs64[64];
    __shared__ float2 gcs[130];
    __shared__ float  dxr[SWZ(L1_ - 1) + 1];
    __shared__ float2 wrli[512];
    __shared__ float  red[4], red2[4];

    const int b = blockIdx.x, tid = threadIdx.x;
    const int lane = tid & 63, wv = tid >> 6;
    const int sloc = *slocp;

    // ---- tables ----
    if (tid < 64) {
        float ang = 0.09817477042468103f * (float)tid;   // 2pi/64
        float s, c; sincosf(ang, &s, &c);
        cs64[tid] = make_float2(c, s);
    }
    if (tid >= 64 && tid < 80) {
        int t = tid - 64;
        float ang = 1.9634954084936207f * (float)t;      // 2pi*5/16
        float s, c; sincosf(ang, &s, &c);
        csl[t] = 1.4142135623730951f * c; ssl[t] = 1.4142135623730951f * s;
    }
    for (int e = tid; e < LENRRC_; e += 256) hl[e] = rrc[e];   // FIX: covers hl[128]
    float v0 = z[(size_t)b * 512 + tid];
    float v1 = z[(size_t)b * 512 + tid + 256];
    __syncthreads();

    // ---- gcs: carrier folded into RRC taps ----
    if (tid < LENRRC_) {
        int neg = (16 - (tid & 15)) & 15;                // (-d) & 15
        gcs[tid] = make_float2(hl[tid] * csl[neg], hl[tid] * ssl[neg]);
    }

    // ---- power norm (single pass: S, Q; ddof=1) ----
    {
        float S = wave_sum(v0 + v1);
        float Q = wave_sum(v0 * v0 + v1 * v1);
        if (lane == 0) { red[wv] = S; red2[wv] = Q; }
    }
    __syncthreads();
    {
        float S = red[0] + red[1] + red[2] + red[3];
        float Q = red2[0] + red2[1] + red2[2] + red2[3];
        float mean = S * (1.f / 512.f);
        float var = (Q - S * mean) * (1.f / 511.f);
        float inv = 1.f / (sqrtf(var) + 1e-8f);
        zl[tid] = (v0 - mean) * inv; zl[tid + 256] = (v1 - mean) * inv;
    }
    __syncthreads();

    // ---- P1: DFT32 (+fftshift folded) ----
    {
        int s = tid >> 5, kk = tid & 31;
        int kk2 = (kk + 16) & 31;
        float sr = 0.f, si = 0.f;
        int t2 = 0;
        for (int q = 0; q < 32; ++q) {
            float2 w = cs64[2 * t2];
            float2 c = *(const float2*)&zl[(s * 32 + q) * 2];
            sr += c.x * w.x + c.y * w.y;                 // * e^{-i ang}
            si += c.y * w.x - c.x * w.y;
            t2 = (t2 + kk2) & 31;
        }
        frfi[s][kk] = make_float2(sr * 0.1767766952966369f, si * 0.1767766952966369f);
    }
    __syncthreads();

    // ---- P2: IDFT64 + CP ----
    #pragma unroll
    for (int e0 = 0; e0 < 2; ++e0) {
        int e = e0 * 256 + tid;
        int s = e >> 6, n = e & 63;
        float dr = 0.f, di = 0.f;
        int t = (sloc * n) & 63;
        for (int k = 0; k < 32; ++k) {
            float2 w = cs64[t];
            float2 f = frfi[s][k];
            dr += f.x * w.x - f.y * w.y;                 // * e^{+i ang}
            di += f.y * w.x + f.x * w.y;
            t = (t + n) & 63;
        }
        float2 d2 = make_float2(dr * 0.125f, di * 0.125f);
        int base = s * 80;
        trti[base + 16 + n] = d2;
        if (n >= 48) trti[base + n - 48] = d2;           // CP
    }
    __syncthreads();

    // ---- P3: upsample x8 + RRC polyphase + carrier -> dxr (swizzled), sumsq ----
    float ss = 0.f;
    for (int a = tid; a < 656; a += 256) {
        float accr[8] = {}, acci[8] = {};
        #pragma unroll 4
        for (int d = 0; d < 16; ++d) {
            int m = a - d;
            bool ok = ((unsigned)m < 640u);
            int mc = ok ? m : 0;
            float2 tv = trti[mc];
            float vr = ok ? tv.x : 0.f;
            float vi = ok ? tv.y : 0.f;
            #pragma unroll
            for (int r = 0; r < 8; ++r) {
                float h = hl[r + 8 * d];
                accr[r] += vr * h; acci[r] += vi * h;
            }
        }
        {   // d=16, tap 128, r=0 only
            int m = a - 16;
            if ((unsigned)m < 640u) {
                float2 tv = trti[m];
                float h = hl[128];
                accr[0] += tv.x * h; acci[0] += tv.y * h;
            }
        }
        int cb = (a & 1) * 8;
        #pragma unroll
        for (int r = 0; r < 8; ++r) {
            float v = accr[r] * csl[cb + r] - acci[r] * ssl[cb + r];
            dxr[SWZ(a * 8 + r)] = v;
            ss += v * v;
        }
    }
    ss = wave_sum(ss);
    if (lane == 0) red[wv] = ss;
    __syncthreads();
    float thr = 1.2f * sqrtf((red[0] + red[1] + red[2] + red[3]) / (float)L1_);
    __syncthreads();

    // ---- P5: clip + PAPR window stats + AWGN (in place) ----
    float pmax = 0.f, psum = 0.f;
    for (int i = tid; i < L1_; i += 256) {
        float x = dxr[SWZ(i)];
        float ax = fabsf(x);
        float over = ax - thr; over = over > 0.f ? over : 0.f;
        float y = (1.f - over / (ax + 1e-8f)) * x;
        if (i >= TSTART_ && i < TSTART_ + NWIN_) { float p = y * y; psum += p; pmax = fmaxf(pmax, p); }
        dxr[SWZ(i)] = y + awgn[(size_t)b * L1_ + i];
    }
    psum = wave_sum(psum); pmax = wave_max(pmax);
    if (lane == 0) { red[wv] = psum; red2[wv] = pmax; }
    __syncthreads();
    if (tid == 0) {
        float sum = red[0] + red[1] + red[2] + red[3];
        float mx = fmaxf(fmaxf(red2[0], red2[1]), fmaxf(red2[2], red2[3]));
        float pdb = 10.f * log10f(mx / (sum / (float)NWIN_));
        papr[b] = pdb;
        out_papr[b] = pdb;
    }
    __syncthreads();     // also guarantees all P5 dxr writes visible before P6

    // ---- P6: matched RRC filter, carrier folded into gcs taps ----
    #pragma unroll
    for (int j0 = 0; j0 < 2; ++j0) {
        int j = j0 * 256 + tid;
        int s = j >> 6, n = j & 63;
        int T = s * 80 + n + 32;                         // Nf/8
        int base = 9 * T;                                // SWZ(Nf)
        int db = 0;
        float ar = 0.f, ai = 0.f;
        for (int e = 0; e < 16; ++e) {
            #pragma unroll
            for (int u = 0; u < 8; ++u) {
                int off = (u == 0) ? 0 : (u + 1);
                float v = dxr[base - off];
                float2 g = gcs[db + u];
                ar += v * g.x; ai += v * g.y;
            }
            base -= 9; db += 8;
        }
        { float v = dxr[base]; float2 g = gcs[128]; ar += v * g.x; ai += v * g.y; }
        float sr = (n & 1) ? -ar : ar;                   // odd n: taps negate
        float si = (n & 1) ? ai : -ai;                   // wil = -(sign*ai)
        wrli[j] = make_float2(sr, si);
    }
    __syncthreads();

    // ---- P7: DFT64 -> band select -> fftshift ----
    {
        int s = tid >> 5, kk = tid & 31;
        int f = sloc + kk;
        float vr = 0.f, vi = 0.f;
        int t = 0;
        for (int n = 0; n < 64; ++n) {
            float2 w = cs64[t];
            float2 d = wrli[s * 64 + n];
            vr += d.x * w.x + d.y * w.y;                 // * e^{-i ang}
            vi += d.y * w.x - d.x * w.y;
            t = (t + f) & 63;
        }
        int ksh = (kk + 16) & 31;
        frfi[s][ksh] = make_float2(vr * 0.125f, vi * 0.125f);
    }
    __syncthreads();

    // ---- P8: IDFT32 -> y5 ----
    {
        int s = tid >> 5, q2 = tid & 31;
        float ur = 0.f, ui = 0.f;
        int t2 = 0;
        for (int k = 0; k < 32; ++k) {
            float2 w = cs64[2 * t2];
            float2 f = frfi[s][k];
            ur += f.x * w.x - f.y * w.y;                 // * e^{+i ang}
            ui += f.y * w.x + f.x * w.y;
            t2 = (t2 + q2) & 31;
        }
        float2 o = make_float2(ur * 0.1767766952966369f, ui * 0.1767766952966369f);
        *(float2*)&y5[(size_t)b * 512 + (s * 32 + q2) * 2] = o;
    }
}

__global__ __launch_bounds__(256) void loss_k(const float* __restrict__ papr,
        float* out_loss) {
    __shared__ float red[4];
    int tid = threadIdx.x, lane = tid & 63, wv = tid >> 6;
    float s = 0.f;
    for (int i = tid; i < 1024; i += 256) { float v = papr[i] - 8.f; s += v > 0.f ? v : 0.f; }
    s = wave_sum(s);
    if (lane == 0) red[wv] = s;
    __syncthreads();
    if (tid == 0) *out_loss = (red[0] + red[1] + red[2] + red[3]) * (1.f / 1024.f);
}

extern "C" void kernel_launch(void* const* d_in, const int* in_sizes, int n_in,
                              void* d_out, int out_size, void* d_ws, size_t ws_size,
                              hipStream_t stream) {
    const float* x    = (const float*)d_in[0];
    const float* Wenc = (const float*)d_in[1];
    const float* benc = (const float*)d_in[2];
    const float* Wdec = (const float*)d_in[3];
    const float* bdec = (const float*)d_in[4];
    const float* rrc  = (const float*)d_in[5];
    const float* awgn = (const float*)d_in[6];
    const int* sloc   = (const int*)d_in[7];
    float* out = (float*)d_out;

    float* ws   = (float*)d_ws;
    float* z    = ws;                    // 1024*512
    float* y5   = z  + 524288;           // 1024*512
    float* papr = y5 + 524288;           // 1024

    float* out_papr = out + (size_t)1024 * 3072;
    float* out_loss = out_papr + 1024;

    initz_k<<<2048, 256, 0, stream>>>(z, benc);
    gemm_mfma_k<8, true>
        <<<dim3(8, 16, 8), 256, 0, stream>>>(x, Wenc, nullptr, z, 1024, 512, 3072);
    mega_k<<<1024, 256, 0, stream>>>(z, rrc, awgn, sloc, y5, papr, out_papr);
    loss_k<<<1, 256, 0, stream>>>(papr, out_loss);
    gemm_mfma_k<1, false>
        <<<dim3(48, 16, 1), 256, 0, stream>>>(y5, Wdec, bdec, out, 1024, 3072, 512);
}

// Round 7
// 215.315 us; speedup vs baseline: 2.3575x; 1.0110x over previous
//
#include <hip/hip_runtime.h>
#include <hip/hip_bf16.h>
#include <math.h>

#define L1_     5248
#define LENRRC_ 129
#define TSTART_ 65
#define NWIN_   5120
#define SWZ(m) ((m) + ((m) >> 3))     // stride-8 reads -> stride-9 -> conflict-free

typedef __attribute__((ext_vector_type(8))) short s16x8;   // 8 bf16 lanes (4 VGPRs)
typedef __attribute__((ext_vector_type(4))) float f32x4;   // MFMA accumulator

// pack fp32 -> (hi bf16 in high16 | lo bf16 in low16); hi is RNE, lo truncated
__device__ inline unsigned pack_pair(float x) {
    unsigned xb = __float_as_uint(x);
    unsigned hi = (xb + 0x7fffu + ((xb >> 16) & 1u)) & 0xffff0000u;
    float lof = x - __uint_as_float(hi);
    return hi | (__float_as_uint(lof) >> 16);
}

__device__ inline float wave_sum(float v) {
    #pragma unroll
    for (int m = 32; m > 0; m >>= 1) v += __shfl_xor(v, m, 64);
    return v;
}
__device__ inline float wave_max(float v) {
    #pragma unroll
    for (int m = 32; m > 0; m >>= 1) v = fmaxf(v, __shfl_xor(v, m, 64));
    return v;
}

// ---------- MFMA GEMM, split bf16 hi/lo, BM=BN=64 BK=32, 4 waves 2x2 ----------
// PARTIAL: write per-z-slice partial sums to C + blockIdx.z*M*N (no atomics)
template<int SK, bool PARTIAL>
__global__ __launch_bounds__(256) void gemm_mfma_k(const float* __restrict__ A,
        const float* __restrict__ W, const float* __restrict__ bias,
        float* __restrict__ C, int M, int N, int K)
{
    __shared__ unsigned Asl[64 * 36];   // [m][k] packed hi|lo, row stride 36
    __shared__ unsigned Bsl[64 * 36];   // [n][k] packed (B transposed)
    const int tid = threadIdx.x;
    const int lane = tid & 63, wave = tid >> 6;
    const int wm = (wave >> 1) * 32, wn = (wave & 1) * 32;
    const int m0 = blockIdx.y * 64, n0 = blockIdx.x * 64;
    int kbeg = 0, kend = K;
    if (SK > 1) { int kch = K / SK; kbeg = blockIdx.z * kch; kend = kbeg + kch; }
    f32x4 acc[2][2] = {};
    const int fm = lane & 15, q = lane >> 4;

    for (int kt = kbeg; kt < kend; kt += 32) {
        #pragma unroll
        for (int i = 0; i < 2; ++i) {            // A tile 64x32
            int flat = i * 1024 + tid * 4;
            int m = flat >> 5, k = flat & 31;
            const float4 v = *(const float4*)(A + (size_t)(m0 + m) * K + kt + k);
            uint4 pk;
            pk.x = pack_pair(v.x); pk.y = pack_pair(v.y);
            pk.z = pack_pair(v.z); pk.w = pack_pair(v.w);
            *(uint4*)&Asl[m * 36 + k] = pk;      // ds_write_b128
        }
        #pragma unroll
        for (int i = 0; i < 2; ++i) {            // B tile 32x64 (transpose)
            int flat = i * 1024 + tid * 4;
            int kk = flat >> 6, n = flat & 63;
            const float4 v = *(const float4*)(W + (size_t)(kt + kk) * N + n0 + n);
            Bsl[n * 36 + kk]       = pack_pair(v.x);
            Bsl[(n + 1) * 36 + kk] = pack_pair(v.y);
            Bsl[(n + 2) * 36 + kk] = pack_pair(v.z);
            Bsl[(n + 3) * 36 + kk] = pack_pair(v.w);
        }
        __syncthreads();

        s16x8 ah[2], al[2], bh[2], bl[2];
        #pragma unroll
        for (int mf = 0; mf < 2; ++mf) {
            const uint4* p = (const uint4*)&Asl[(wm + mf * 16 + fm) * 36 + q * 8];
            uint4 p0 = p[0], p1 = p[1];
            uint4 hu, lu;
            hu.x = (p0.x >> 16) | (p0.y & 0xffff0000u);
            hu.y = (p0.z >> 16) | (p0.w & 0xffff0000u);
            hu.z = (p1.x >> 16) | (p1.y & 0xffff0000u);
            hu.w = (p1.z >> 16) | (p1.w & 0xffff0000u);
            lu.x = (p0.x & 0xffffu) | (p0.y << 16);
            lu.y = (p0.z & 0xffffu) | (p0.w << 16);
            lu.z = (p1.x & 0xffffu) | (p1.y << 16);
            lu.w = (p1.z & 0xffffu) | (p1.w << 16);
            ah[mf] = __builtin_bit_cast(s16x8, hu);
            al[mf] = __builtin_bit_cast(s16x8, lu);
        }
        #pragma unroll
        for (int nf = 0; nf < 2; ++nf) {
            const uint4* p = (const uint4*)&Bsl[(wn + nf * 16 + fm) * 36 + q * 8];
            uint4 p0 = p[0], p1 = p[1];
            uint4 hu, lu;
            hu.x = (p0.x >> 16) | (p0.y & 0xffff0000u);
            hu.y = (p0.z >> 16) | (p0.w & 0xffff0000u);
            hu.z = (p1.x >> 16) | (p1.y & 0xffff0000u);
            hu.w = (p1.z >> 16) | (p1.w & 0xffff0000u);
            lu.x = (p0.x & 0xffffu) | (p0.y << 16);
            lu.y = (p0.z & 0xffffu) | (p0.w << 16);
            lu.z = (p1.x & 0xffffu) | (p1.y << 16);
            lu.w = (p1.z & 0xffffu) | (p1.w << 16);
            bh[nf] = __builtin_bit_cast(s16x8, hu);
            bl[nf] = __builtin_bit_cast(s16x8, lu);
        }
        #pragma unroll
        for (int mf = 0; mf < 2; ++mf)
            #pragma unroll
            for (int nf = 0; nf < 2; ++nf) {
                acc[mf][nf] = __builtin_amdgcn_mfma_f32_16x16x32_bf16(ah[mf], bh[nf], acc[mf][nf], 0, 0, 0);
                acc[mf][nf] = __builtin_amdgcn_mfma_f32_16x16x32_bf16(ah[mf], bl[nf], acc[mf][nf], 0, 0, 0);
                acc[mf][nf] = __builtin_amdgcn_mfma_f32_16x16x32_bf16(al[mf], bh[nf], acc[mf][nf], 0, 0, 0);
            }
        __syncthreads();
    }

    float* Cb = PARTIAL ? (C + (size_t)blockIdx.z * M * N) : C;
    #pragma unroll
    for (int mf = 0; mf < 2; ++mf)
        #pragma unroll
        for (int nf = 0; nf < 2; ++nf)
            #pragma unroll
            for (int r = 0; r < 4; ++r) {
                int m = m0 + wm + mf * 16 + q * 4 + r;
                int n = n0 + wn + nf * 16 + fm;
                if constexpr (PARTIAL) Cb[(size_t)m * N + n] = acc[mf][nf][r];
                else Cb[(size_t)m * N + n] = acc[mf][nf][r] + bias[n];
            }
}

// ---------- sum 8 K-slices + bias -> z ----------
__global__ __launch_bounds__(256) void reduce_k(const float* __restrict__ zp,
        const float* __restrict__ bias, float* __restrict__ z) {
    int i = blockIdx.x * 256 + threadIdx.x;          // 524288 total
    float s = bias[i & 511];
    #pragma unroll
    for (int k = 0; k < 8; ++k) s += zp[(size_t)k * 524288 + i];
    z[i] = s;
}

// ---------- megakernel: one block per batch row, whole signal chain in LDS ----------
__global__ __launch_bounds__(256) void mega_k(const float* __restrict__ z,
        const float* __restrict__ rrc, const float* __restrict__ awgn,
        const int* __restrict__ slocp, float* __restrict__ y5, float* __restrict__ papr,
        float* __restrict__ out_papr)
{
    __shared__ float  zl[512];
    __shared__ float2 frfi[8][32];
    __shared__ float2 trti[640];
    __shared__ float  hl[132];
    __shared__ float  csl[16], ssl[16];
    __shared__ float2 cs64[64];
    __shared__ float2 gcs[130];
    __shared__ float  dxr[SWZ(L1_ - 1) + 1];
    __shared__ float2 wrli[512];
    __shared__ float  red[4], red2[4];

    const int b = blockIdx.x, tid = threadIdx.x;
    const int lane = tid & 63, wv = tid >> 6;
    const int sloc = *slocp;

    // ---- tables ----
    if (tid < 64) {
        float ang = 0.09817477042468103f * (float)tid;   // 2pi/64
        float s, c; sincosf(ang, &s, &c);
        cs64[tid] = make_float2(c, s);
    }
    if (tid >= 64 && tid < 80) {
        int t = tid - 64;
        float ang = 1.9634954084936207f * (float)t;      // 2pi*5/16
        float s, c; sincosf(ang, &s, &c);
        csl[t] = 1.4142135623730951f * c; ssl[t] = 1.4142135623730951f * s;
    }
    for (int e = tid; e < LENRRC_; e += 256) hl[e] = rrc[e];
    float v0 = z[(size_t)b * 512 + tid];
    float v1 = z[(size_t)b * 512 + tid + 256];
    __syncthreads();

    // ---- gcs: carrier folded into RRC taps ----
    if (tid < LENRRC_) {
        int neg = (16 - (tid & 15)) & 15;                // (-d) & 15
        gcs[tid] = make_float2(hl[tid] * csl[neg], hl[tid] * ssl[neg]);
    }

    // ---- power norm (single pass: S, Q; ddof=1) ----
    {
        float S = wave_sum(v0 + v1);
        float Q = wave_sum(v0 * v0 + v1 * v1);
        if (lane == 0) { red[wv] = S; red2[wv] = Q; }
    }
    __syncthreads();
    {
        float S = red[0] + red[1] + red[2] + red[3];
        float Q = red2[0] + red2[1] + red2[2] + red2[3];
        float mean = S * (1.f / 512.f);
        float var = (Q - S * mean) * (1.f / 511.f);
        float inv = 1.f / (sqrtf(var) + 1e-8f);
        zl[tid] = (v0 - mean) * inv; zl[tid + 256] = (v1 - mean) * inv;
    }
    __syncthreads();

    // ---- P1: DFT32 (+fftshift folded) ----
    {
        int s = tid >> 5, kk = tid & 31;
        int kk2 = (kk + 16) & 31;
        float sr = 0.f, si = 0.f;
        int t2 = 0;
        for (int q = 0; q < 32; ++q) {
            float2 w = cs64[2 * t2];
            float2 c = *(const float2*)&zl[(s * 32 + q) * 2];
            sr += c.x * w.x + c.y * w.y;                 // * e^{-i ang}
            si += c.y * w.x - c.x * w.y;
            t2 = (t2 + kk2) & 31;
        }
        frfi[s][kk] = make_float2(sr * 0.1767766952966369f, si * 0.1767766952966369f);
    }
    __syncthreads();

    // ---- P2: IDFT64 + CP ----
    #pragma unroll
    for (int e0 = 0; e0 < 2; ++e0) {
        int e = e0 * 256 + tid;
        int s = e >> 6, n = e & 63;
        float dr = 0.f, di = 0.f;
        int t = (sloc * n) & 63;
        for (int k = 0; k < 32; ++k) {
            float2 w = cs64[t];
            float2 f = frfi[s][k];
            dr += f.x * w.x - f.y * w.y;                 // * e^{+i ang}
            di += f.y * w.x + f.x * w.y;
            t = (t + n) & 63;
        }
        float2 d2 = make_float2(dr * 0.125f, di * 0.125f);
        int base = s * 80;
        trti[base + 16 + n] = d2;
        if (n >= 48) trti[base + n - 48] = d2;           // CP
    }
    __syncthreads();

    // ---- P3: upsample x8 + RRC polyphase + carrier -> dxr (swizzled), sumsq ----
    float ss = 0.f;
    for (int a = tid; a < 656; a += 256) {
        float accr[8] = {}, acci[8] = {};
        #pragma unroll 4
        for (int d = 0; d < 16; ++d) {
            int m = a - d;
            bool ok = ((unsigned)m < 640u);
            int mc = ok ? m : 0;
            float2 tv = trti[mc];
            float vr = ok ? tv.x : 0.f;
            float vi = ok ? tv.y : 0.f;
            #pragma unroll
            for (int r = 0; r < 8; ++r) {
                float h = hl[r + 8 * d];
                accr[r] += vr * h; acci[r] += vi * h;
            }
        }
        {   // d=16, tap 128, r=0 only
            int m = a - 16;
            if ((unsigned)m < 640u) {
                float2 tv = trti[m];
                float h = hl[128];
                accr[0] += tv.x * h; acci[0] += tv.y * h;
            }
        }
        int cb = (a & 1) * 8;
        #pragma unroll
        for (int r = 0; r < 8; ++r) {
            float v = accr[r] * csl[cb + r] - acci[r] * ssl[cb + r];
            dxr[SWZ(a * 8 + r)] = v;
            ss += v * v;
        }
    }
    ss = wave_sum(ss);
    if (lane == 0) red[wv] = ss;
    __syncthreads();
    float thr = 1.2f * sqrtf((red[0] + red[1] + red[2] + red[3]) / (float)L1_);
    __syncthreads();

    // ---- P5: clip + PAPR window stats + AWGN (in place) ----
    float pmax = 0.f, psum = 0.f;
    for (int i = tid; i < L1_; i += 256) {
        float x = dxr[SWZ(i)];
        float ax = fabsf(x);
        float over = ax - thr; over = over > 0.f ? over : 0.f;
        float y = (1.f - over / (ax + 1e-8f)) * x;
        if (i >= TSTART_ && i < TSTART_ + NWIN_) { float p = y * y; psum += p; pmax = fmaxf(pmax, p); }
        dxr[SWZ(i)] = y + awgn[(size_t)b * L1_ + i];
    }
    psum = wave_sum(psum); pmax = wave_max(pmax);
    if (lane == 0) { red[wv] = psum; red2[wv] = pmax; }
    __syncthreads();
    if (tid == 0) {
        float sum = red[0] + red[1] + red[2] + red[3];
        float mx = fmaxf(fmaxf(red2[0], red2[1]), fmaxf(red2[2], red2[3]));
        float pdb = 10.f * log10f(mx / (sum / (float)NWIN_));
        papr[b] = pdb;
        out_papr[b] = pdb;
    }
    __syncthreads();     // also guarantees all P5 dxr writes visible before P6

    // ---- P6: matched RRC filter, carrier folded into gcs taps ----
    #pragma unroll
    for (int j0 = 0; j0 < 2; ++j0) {
        int j = j0 * 256 + tid;
        int s = j >> 6, n = j & 63;
        int T = s * 80 + n + 32;                         // Nf/8
        int base = 9 * T;                                // SWZ(Nf)
        int db = 0;
        float ar = 0.f, ai = 0.f;
        for (int e = 0; e < 16; ++e) {
            #pragma unroll
            for (int u = 0; u < 8; ++u) {
                int off = (u == 0) ? 0 : (u + 1);
                float v = dxr[base - off];
                float2 g = gcs[db + u];
                ar += v * g.x; ai += v * g.y;
            }
            base -= 9; db += 8;
        }
        { float v = dxr[base]; float2 g = gcs[128]; ar += v * g.x; ai += v * g.y; }
        float sr = (n & 1) ? -ar : ar;                   // odd n: taps negate
        float si = (n & 1) ? ai : -ai;                   // wil = -(sign*ai)
        wrli[j] = make_float2(sr, si);
    }
    __syncthreads();

    // ---- P7: DFT64 -> band select -> fftshift ----
    {
        int s = tid >> 5, kk = tid & 31;
        int f = sloc + kk;
        float vr = 0.f, vi = 0.f;
        int t = 0;
        for (int n = 0; n < 64; ++n) {
            float2 w = cs64[t];
            float2 d = wrli[s * 64 + n];
            vr += d.x * w.x + d.y * w.y;                 // * e^{-i ang}
            vi += d.y * w.x - d.x * w.y;
            t = (t + f) & 63;
        }
        int ksh = (kk + 16) & 31;
        frfi[s][ksh] = make_float2(vr * 0.125f, vi * 0.125f);
    }
    __syncthreads();

    // ---- P8: IDFT32 -> y5 ----
    {
        int s = tid >> 5, q2 = tid & 31;
        float ur = 0.f, ui = 0.f;
        int t2 = 0;
        for (int k = 0; k < 32; ++k) {
            float2 w = cs64[2 * t2];
            float2 f = frfi[s][k];
            ur += f.x * w.x - f.y * w.y;                 // * e^{+i ang}
            ui += f.y * w.x + f.x * w.y;
            t2 = (t2 + q2) & 31;
        }
        float2 o = make_float2(ur * 0.1767766952966369f, ui * 0.1767766952966369f);
        *(float2*)&y5[(size_t)b * 512 + (s * 32 + q2) * 2] = o;
    }
}

__global__ __launch_bounds__(256) void loss_k(const float* __restrict__ papr,
        float* out_loss) {
    __shared__ float red[4];
    int tid = threadIdx.x, lane = tid & 63, wv = tid >> 6;
    float s = 0.f;
    for (int i = tid; i < 1024; i += 256) { float v = papr[i] - 8.f; s += v > 0.f ? v : 0.f; }
    s = wave_sum(s);
    if (lane == 0) red[wv] = s;
    __syncthreads();
    if (tid == 0) *out_loss = (red[0] + red[1] + red[2] + red[3]) * (1.f / 1024.f);
}

extern "C" void kernel_launch(void* const* d_in, const int* in_sizes, int n_in,
                              void* d_out, int out_size, void* d_ws, size_t ws_size,
                              hipStream_t stream) {
    const float* x    = (const float*)d_in[0];
    const float* Wenc = (const float*)d_in[1];
    const float* benc = (const float*)d_in[2];
    const float* Wdec = (const float*)d_in[3];
    const float* bdec = (const float*)d_in[4];
    const float* rrc  = (const float*)d_in[5];
    const float* awgn = (const float*)d_in[6];
    const int* sloc   = (const int*)d_in[7];
    float* out = (float*)d_out;

    float* ws   = (float*)d_ws;
    float* zp   = ws;                    // 8 * 1024*512 partial slices (16.8 MB)
    float* z    = zp + 8 * 524288;       // 1024*512
    float* y5   = z  + 524288;           // 1024*512
    float* papr = y5 + 524288;           // 1024

    float* out_papr = out + (size_t)1024 * 3072;
    float* out_loss = out_papr + 1024;

    gemm_mfma_k<8, true>
        <<<dim3(8, 16, 8), 256, 0, stream>>>(x, Wenc, nullptr, zp, 1024, 512, 3072);
    reduce_k<<<2048, 256, 0, stream>>>(zp, benc, z);
    mega_k<<<1024, 256, 0, stream>>>(z, rrc, awgn, sloc, y5, papr, out_papr);
    loss_k<<<1, 256, 0, stream>>>(papr, out_loss);
    gemm_mfma_k<1, false>
        <<<dim3(48, 16, 1), 256, 0, stream>>>(y5, Wdec, bdec, out, 1024, 3072, 512);
}